// Round 6
// baseline (354.315 us; speedup 1.0000x reference)
//
#include <hip/hip_runtime.h>

// AttentionFusion: fused = sigmoid(x1.w - x2.w)*x1 + (1-sig)*x2, per row.
// N=16384 rows, D=2048 cols, fp32.
//
// v6: explicit two-pass split.
// Five single-pass variants (block-per-row, wave-per-row, 8-row pipeline,
// 2-row concurrent, LDS-staged) all pinned at 109-115 us / 2.4 TB/s HBM:
// the coupled load-burst -> reduce -> barrier -> store phase structure keeps
// resident blocks in lockstep, so HBM demand is bursty/correlated and the
// chip idles between surges. Also, hipcc rematerializes the fuse-phase
// reads anyway (VGPR pinned at 20-32), so single-pass was secretly
// two-pass. Make it explicit, giving each pass its ideal shape:
//   Pass 1 (dot):  block-per-row reduce, writes only alpha[N][2] (128 KB).
//                  Leaves x1+x2 (256 MiB = L3 size) Infinity-Cache-resident.
//   Pass 2 (fuse): pure grid-stride elementwise stream - no barriers, no
//                  reduction, continuous uniform issue (the shape that
//                  reaches ~6 TB/s in ubench). alpha is wave-uniform
//                  (64 | 512) and L2-hot. NT stores keep the output stream
//                  from evicting x1/x2 from L3.

#define NROWS 16384
#define DCOLS 2048
#define NF4 ((size_t)NROWS * (DCOLS / 4))   // 8,388,608 float4 elements

typedef float f32x4 __attribute__((ext_vector_type(4)));

// ---------------------------------------------------------------- pass 1
__global__ __launch_bounds__(256) void dot_kernel(
    const float* __restrict__ x1,
    const float* __restrict__ x2,
    const float* __restrict__ w,
    float* __restrict__ alpha)
{
    const int t = threadIdx.x;
    const int wave = t >> 6;
    const int lane = t & 63;
    const size_t row = blockIdx.x;

    const f32x4* __restrict__ x1v = (const f32x4*)(x1 + row * DCOLS);
    const f32x4* __restrict__ x2v = (const f32x4*)(x2 + row * DCOLS);
    const f32x4* __restrict__ wv  = (const f32x4*)w;

    // 512 float4 per row, 256 threads -> 2 per thread, coalesced.
    const f32x4 a0 = x1v[t];
    const f32x4 a1 = x1v[t + 256];
    const f32x4 b0 = x2v[t];
    const f32x4 b1 = x2v[t + 256];
    const f32x4 w0 = wv[t];          // w is 8 KiB, L1/L2-hot
    const f32x4 w1 = wv[t + 256];

    float p = 0.0f;
    p = fmaf(a0.x - b0.x, w0.x, p);
    p = fmaf(a0.y - b0.y, w0.y, p);
    p = fmaf(a0.z - b0.z, w0.z, p);
    p = fmaf(a0.w - b0.w, w0.w, p);
    p = fmaf(a1.x - b1.x, w1.x, p);
    p = fmaf(a1.y - b1.y, w1.y, p);
    p = fmaf(a1.z - b1.z, w1.z, p);
    p = fmaf(a1.w - b1.w, w1.w, p);

    #pragma unroll
    for (int off = 32; off > 0; off >>= 1)
        p += __shfl_down(p, off, 64);

    __shared__ float wsum[4];
    if (lane == 0) wsum[wave] = p;
    __syncthreads();

    if (t == 0) {
        const float d = wsum[0] + wsum[1] + wsum[2] + wsum[3];
        const float g = 1.0f / (1.0f + expf(-d));   // alpha1 = sigmoid(s1-s2)
        alpha[row * 2]     = g;
        alpha[row * 2 + 1] = 1.0f - g;
    }
}

// ---------------------------------------------------------------- pass 2
// Pure elementwise stream. 2048 blocks x 256 thr, 16 f32x4 per thread.
// Row index = i >> 9 is wave-uniform (512 f32x4 per row, 64 | 512).
__global__ __launch_bounds__(256) void fuse_kernel(
    const float* __restrict__ x1,
    const float* __restrict__ x2,
    const float* __restrict__ alpha,
    float* __restrict__ fused)
{
    const f32x4* __restrict__ av = (const f32x4*)x1;
    const f32x4* __restrict__ bv = (const f32x4*)x2;
    f32x4* __restrict__ ov = (f32x4*)fused;

    const size_t stride = (size_t)gridDim.x * 256;
    size_t i = (size_t)blockIdx.x * 256 + threadIdx.x;

    #pragma unroll 4
    for (; i < NF4; i += stride) {
        const float g = alpha[(i >> 9) << 1];   // alpha1 for this row
        const f32x4 a = av[i];
        const f32x4 b = bv[i];
        f32x4 f;
        f.x = fmaf(g, a.x - b.x, b.x);
        f.y = fmaf(g, a.y - b.y, b.y);
        f.z = fmaf(g, a.z - b.z, b.z);
        f.w = fmaf(g, a.w - b.w, b.w);
        // NT: don't let the 128 MiB output stream evict x1/x2 from L3.
        __builtin_nontemporal_store(f, ov + i);
    }
}

extern "C" void kernel_launch(void* const* d_in, const int* in_sizes, int n_in,
                              void* d_out, int out_size, void* d_ws, size_t ws_size,
                              hipStream_t stream)
{
    const float* x1 = (const float*)d_in[0];
    const float* x2 = (const float*)d_in[1];
    const float* w  = (const float*)d_in[2];

    float* fused = (float*)d_out;                       // [N, D]
    float* alpha = fused + (size_t)NROWS * DCOLS;       // [N, 2]

    dot_kernel<<<NROWS, 256, 0, stream>>>(x1, x2, w, alpha);
    fuse_kernel<<<2048, 256, 0, stream>>>(x1, x2, alpha, fused);
}